// Round 1
// baseline (1087.500 us; speedup 1.0000x reference)
//
#include <hip/hip_runtime.h>
#include <math.h>

#define N_NODES 50000
#define N_EDGES 800000
#define R_REL 8
#define H_DIM 128
#define C_OUT 64

// ---------------- CSR build (dst-sorted edge list) ----------------

__global__ void k_hist(const int* __restrict__ dst, int* __restrict__ hist) {
  int e = blockIdx.x * blockDim.x + threadIdx.x;
  if (e < N_EDGES) atomicAdd(&hist[dst[e]], 1);
}

__global__ void k_scan(const int* __restrict__ hist, int* __restrict__ rowptr,
                       int* __restrict__ cursor) {
  __shared__ int tmp[1024];
  int tid = threadIdx.x;
  int carry = 0;
  for (int base = 0; base < N_NODES; base += 1024) {
    int idx = base + tid;
    int v = (idx < N_NODES) ? hist[idx] : 0;
    tmp[tid] = v;
    __syncthreads();
    for (int off = 1; off < 1024; off <<= 1) {
      int t = (tid >= off) ? tmp[tid - off] : 0;
      __syncthreads();
      tmp[tid] += t;
      __syncthreads();
    }
    int excl = carry + tmp[tid] - v;
    if (idx < N_NODES) { rowptr[idx] = excl; cursor[idx] = excl; }
    carry += tmp[1023];
    __syncthreads();
  }
  if (tid == 0) rowptr[N_NODES] = carry;
}

__global__ void k_scatter(const int* __restrict__ src, const int* __restrict__ dst,
                          const int* __restrict__ et, int* __restrict__ cursor,
                          int* __restrict__ ssrc, int* __restrict__ setype) {
  int e = blockIdx.x * blockDim.x + threadIdx.x;
  if (e < N_EDGES) {
    int d = dst[e];
    int p = atomicAdd(&cursor[d], 1);
    ssrc[p] = src[e];
    setype[p] = et[e];
  }
}

// ---------------- per-relation transform: xr[n,r,:] = X[n,:] @ W[r], plus qx/kx ----------------
// grid = (ceil(N/64), R), block = 256. LDS: 32KB W-chunk + 16KB X-chunk = 48KB.
// thread -> og = output group (4 consecutive outputs), ng = node group (8 nodes). 32 acc regs.

__global__ __launch_bounds__(256) void k_transform(
    const float* __restrict__ X, const float* __restrict__ W,
    const float* __restrict__ qv, const float* __restrict__ kv,
    float* __restrict__ xr, float* __restrict__ qx, float* __restrict__ kx)
{
  __shared__ float sW[64 * 128];  // 32 KB: W[f_chunk][o]
  __shared__ float sX[64 * 64];   // 16 KB: X^T[f_chunk][n]
  const int r  = blockIdx.y;
  const int n0 = blockIdx.x * 64;
  const int tid = threadIdx.x;
  const int og = tid & 31;   // outputs 4*og..4*og+3
  const int ng = tid >> 5;   // nodes ng*8..ng*8+7

  float acc[8][4];
#pragma unroll
  for (int i = 0; i < 8; ++i) {
    acc[i][0] = 0.f; acc[i][1] = 0.f; acc[i][2] = 0.f; acc[i][3] = 0.f;
  }
  const float4 zero4 = make_float4(0.f, 0.f, 0.f, 0.f);

  for (int kb = 0; kb < 2; ++kb) {
    __syncthreads();
    const float4* Wv = (const float4*)(W + ((size_t)r * 128 + (size_t)kb * 64) * 128);
    float4* sWv = (float4*)sW;
#pragma unroll
    for (int i = 0; i < 8; ++i) sWv[tid + i * 256] = Wv[tid + i * 256];
#pragma unroll
    for (int i = 0; i < 4; ++i) {
      int li = tid + i * 256;          // 0..1023 = 64 nodes * 16 float4
      int n = li >> 4, j = li & 15;
      int gn = n0 + n;
      float4 v = (gn < N_NODES) ? ((const float4*)(X + (size_t)gn * 128))[kb * 16 + j] : zero4;
      sX[(j * 4 + 0) * 64 + n] = v.x;
      sX[(j * 4 + 1) * 64 + n] = v.y;
      sX[(j * 4 + 2) * 64 + n] = v.z;
      sX[(j * 4 + 3) * 64 + n] = v.w;
    }
    __syncthreads();
#pragma unroll 4
    for (int fl = 0; fl < 64; ++fl) {
      float4 w4 = *(const float4*)(sW + fl * 128 + og * 4);
      float4 xa = *(const float4*)(sX + fl * 64 + ng * 8);
      float4 xb = *(const float4*)(sX + fl * 64 + ng * 8 + 4);
      float xn[8] = {xa.x, xa.y, xa.z, xa.w, xb.x, xb.y, xb.z, xb.w};
#pragma unroll
      for (int i = 0; i < 8; ++i) {
        acc[i][0] += xn[i] * w4.x;
        acc[i][1] += xn[i] * w4.y;
        acc[i][2] += xn[i] * w4.z;
        acc[i][3] += xn[i] * w4.w;
      }
    }
  }

  __syncthreads();
  float4 q4 = ((const float4*)qv)[og];
  float4 k4 = ((const float4*)kv)[og];
#pragma unroll
  for (int i = 0; i < 8; ++i) {
    int gn = n0 + ng * 8 + i;
    float4 o4 = make_float4(acc[i][0], acc[i][1], acc[i][2], acc[i][3]);
    if (gn < N_NODES)
      ((float4*)(xr + ((size_t)gn * R_REL + r) * 128))[og] = o4;
    sX[(ng * 8 + i) * 32 + og] = o4.x * q4.x + o4.y * q4.y + o4.z * q4.z + o4.w * q4.w;
    sW[(ng * 8 + i) * 32 + og] = o4.x * k4.x + o4.y * k4.y + o4.z * k4.z + o4.w * k4.w;
  }
  __syncthreads();
  if (tid < 64) {
    int gn = n0 + tid;
    float sq = 0.f, sk = 0.f;
#pragma unroll
    for (int t = 0; t < 32; ++t) { sq += sX[tid * 32 + t]; sk += sW[tid * 32 + t]; }
    if (gn < N_NODES) { qx[gn * R_REL + r] = sq; kx[gn * R_REL + r] = sk; }
  }
}

// ---------------- per-dst-node online-softmax aggregation ----------------
// grid = N, block = 64 (one wave per node). Lane l handles features 2l, 2l+1.

__global__ __launch_bounds__(64) void k_agg(
    const float* __restrict__ xr, const float* __restrict__ qx, const float* __restrict__ kx,
    const int* __restrict__ rowptr, const int* __restrict__ ssrc, const int* __restrict__ setype,
    const float* __restrict__ bias, float* __restrict__ out)
{
  const int nd = blockIdx.x;
  const int lane = threadIdx.x;
  const int s = rowptr[nd];
  const int deg = rowptr[nd + 1] - s;

  float m = -INFINITY, sum = 0.f, ax = 0.f, ay = 0.f;
  const float2* xr2 = (const float2*)xr;

  for (int c = 0; c < deg; c += 64) {
    int idx = c + lane;
    bool valid = idx < deg;
    int sn = 0, et = 0;
    float a = -INFINITY;
    if (valid) {
      sn = ssrc[s + idx];
      et = setype[s + idx];
      a = qx[nd * R_REL + et] + kx[sn * R_REL + et];
      a = (a >= 0.f) ? a : 0.2f * a;   // leaky relu, slope 0.2
    }
    float cm = a;
#pragma unroll
    for (int off = 32; off > 0; off >>= 1) cm = fmaxf(cm, __shfl_xor(cm, off));
    float mnew = fmaxf(m, cm);
    float scale = (m == -INFINITY) ? 0.f : __expf(m - mnew);
    sum *= scale; ax *= scale; ay *= scale;
    m = mnew;
    float e = valid ? __expf(a - m) : 0.f;
    float cs = e;
#pragma unroll
    for (int off = 32; off > 0; off >>= 1) cs += __shfl_xor(cs, off);
    sum += cs;
    int cnt = (deg - c < 64) ? (deg - c) : 64;
    for (int j = 0; j < cnt; ++j) {
      float w = __shfl(e, j);
      int sj = __shfl(sn, j);
      int ej = __shfl(et, j);
      float2 v = xr2[((size_t)sj * R_REL + ej) * 64 + lane];
      ax += w * v.x;
      ay += w * v.y;
    }
  }
  float inv = (deg > 0) ? 1.f / sum : 0.f;
  float2 bb = ((const float2*)bias)[lane];
  float ox = fmaxf(ax * inv + bb.x, 0.f);
  float oy = fmaxf(ay * inv + bb.y, 0.f);
  ((float2*)out)[(size_t)nd * 64 + lane] = make_float2(ox, oy);
}

// ---------------- final linear + log_softmax ----------------
// grid = N, block = 64 (lane = class c).

__global__ __launch_bounds__(64) void k_final(
    const float* __restrict__ h, const float* __restrict__ lw, const float* __restrict__ lb,
    float* __restrict__ out)
{
  const int nd = blockIdx.x;
  const int c = threadIdx.x;
  const float* hrow = h + (size_t)nd * 128;
  float acc = lb[c];
#pragma unroll 8
  for (int f = 0; f < 128; ++f) acc += hrow[f] * lw[f * 64 + c];
  float mx = acc;
#pragma unroll
  for (int off = 32; off > 0; off >>= 1) mx = fmaxf(mx, __shfl_xor(mx, off));
  float e = __expf(acc - mx);
  float ssum = e;
#pragma unroll
  for (int off = 32; off > 0; off >>= 1) ssum += __shfl_xor(ssum, off);
  out[(size_t)nd * 64 + c] = acc - mx - __logf(ssum);
}

// ---------------- launch ----------------

extern "C" void kernel_launch(void* const* d_in, const int* in_sizes, int n_in,
                              void* d_out, int out_size, void* d_ws, size_t ws_size,
                              hipStream_t stream) {
  const float* x   = (const float*)d_in[0];
  const int* ei    = (const int*)d_in[1];
  const int* etype = (const int*)d_in[2];
  const float* W1 = (const float*)d_in[3];
  const float* q1 = (const float*)d_in[4];
  const float* k1 = (const float*)d_in[5];
  const float* b1 = (const float*)d_in[6];
  const float* W2 = (const float*)d_in[7];
  const float* q2 = (const float*)d_in[8];
  const float* k2 = (const float*)d_in[9];
  const float* b2 = (const float*)d_in[10];
  const float* W3 = (const float*)d_in[11];
  const float* q3 = (const float*)d_in[12];
  const float* k3 = (const float*)d_in[13];
  const float* b3 = (const float*)d_in[14];
  const float* lw = (const float*)d_in[15];
  const float* lb = (const float*)d_in[16];
  float* outp = (float*)d_out;

  char* p = (char*)d_ws;
  auto alloc = [&](size_t bytes) {
    char* r = p;
    p += (bytes + 255) & ~(size_t)255;
    return r;
  };
  float* xr   = (float*)alloc((size_t)N_NODES * R_REL * H_DIM * 4);  // 204.8 MB
  float* qx   = (float*)alloc((size_t)N_NODES * R_REL * 4);
  float* kx   = (float*)alloc((size_t)N_NODES * R_REL * 4);
  float* hA   = (float*)alloc((size_t)N_NODES * H_DIM * 4);
  float* hB   = (float*)alloc((size_t)N_NODES * H_DIM * 4);
  int* rowptr = (int*)alloc((size_t)(N_NODES + 1) * 4);
  int* cursor = (int*)alloc((size_t)N_NODES * 4);
  int* hist   = (int*)alloc((size_t)N_NODES * 4);
  int* ssrc   = (int*)alloc((size_t)N_EDGES * 4);
  int* setype = (int*)alloc((size_t)N_EDGES * 4);

  const int* src = ei;            // edge_index[0]
  const int* dst = ei + N_EDGES;  // edge_index[1]

  // CSR build (graph is static per call, rebuilt each launch as required)
  hipMemsetAsync(hist, 0, (size_t)N_NODES * 4, stream);
  k_hist<<<(N_EDGES + 255) / 256, 256, 0, stream>>>(dst, hist);
  k_scan<<<1, 1024, 0, stream>>>(hist, rowptr, cursor);
  k_scatter<<<(N_EDGES + 255) / 256, 256, 0, stream>>>(src, dst, etype, cursor, ssrc, setype);

  dim3 tgrid((N_NODES + 63) / 64, R_REL);

  // layer 1
  k_transform<<<tgrid, 256, 0, stream>>>(x, W1, q1, k1, xr, qx, kx);
  k_agg<<<N_NODES, 64, 0, stream>>>(xr, qx, kx, rowptr, ssrc, setype, b1, hA);
  // layer 2
  k_transform<<<tgrid, 256, 0, stream>>>(hA, W2, q2, k2, xr, qx, kx);
  k_agg<<<N_NODES, 64, 0, stream>>>(xr, qx, kx, rowptr, ssrc, setype, b2, hB);
  // layer 3
  k_transform<<<tgrid, 256, 0, stream>>>(hB, W3, q3, k3, xr, qx, kx);
  k_agg<<<N_NODES, 64, 0, stream>>>(xr, qx, kx, rowptr, ssrc, setype, b3, hA);
  // final linear + log_softmax
  k_final<<<N_NODES, 64, 0, stream>>>(hA, lw, lb, outp);
}